// Round 7
// baseline (796.827 us; speedup 1.0000x reference)
//
#include <hip/hip_runtime.h>
#include <stdint.h>

#define M_DIM 4096
#define K_DIM 4096
#define N_DIM 11008

typedef _Float16 half2v __attribute__((ext_vector_type(2)));
typedef _Float16 half8  __attribute__((ext_vector_type(8)));
typedef float    f32x4  __attribute__((ext_vector_type(4)));

// cvt_pkrtz returns __fp16x2; route through bits to avoid clang's
// _Float16/__fp16 vector-type incompatibility.
__device__ __forceinline__ unsigned int pkrtz_bits(float a, float b) {
  typedef __fp16 fp16x2 __attribute__((ext_vector_type(2)));
  union { fp16x2 h; unsigned int u; } c;
  c.h = __builtin_amdgcn_cvt_pkrtz(a, b);
  return c.u;
}

// Pack 8 f32 (k0..k7, exactly-fp16-valued) into fp16 in Marlin order
// {k0,k4,k1,k5,k2,k6,k3,k7}. RTZ is exact here (values are fp16-representable).
__device__ __forceinline__ half8 pack8(float4 lo, float4 hi) {
  union { unsigned int u[4]; half8 v; } r;
  r.u[0] = pkrtz_bits(lo.x, hi.x);
  r.u[1] = pkrtz_bits(lo.y, hi.y);
  r.u[2] = pkrtz_bits(lo.z, hi.z);
  r.u[3] = pkrtz_bits(lo.w, hi.w);
  return r.v;
}

// Pre-pass: X f32 [M][K] -> fp16 [M][K], k-permuted within each group of 8.
__global__ __launch_bounds__(256) void convert_x(const float* __restrict__ X,
                                                 _Float16* __restrict__ X16) {
  size_t g = (size_t)blockIdx.x * 256 + threadIdx.x;   // one 8-group per thread
  const float4* p = (const float4*)(X + g * 8);
  float4 lo = p[0], hi = p[1];
  *(half8*)(X16 + g * 8) = pack8(lo, hi);
}

// 8 nibbles (one packed dword, k along nibbles) -> 8 fp16 weights (q - (z+1)),
// in Marlin order {0,4,1,5,2,6,3,7}. zoff = half2(1025+z, 1025+z) as bits.
// (q&0x000F000F)|0x64006400 = fp16 pair (1024+n_j, 1024+n_{j+4}); one pk_sub each.
__device__ __forceinline__ half8 unpack8(unsigned int q, half2v zoff) {
  union { unsigned int u; half2v h; } t0, t1, t2, t3;
  t0.u = (q & 0x000F000Fu) | 0x64006400u;
  t1.u = ((q >> 4) & 0x000F000Fu) | 0x64006400u;
  t2.u = ((q >> 8) & 0x000F000Fu) | 0x64006400u;
  t3.u = ((q >> 12) & 0x000F000Fu) | 0x64006400u;
  union { half2v h[4]; half8 v; } r;
  r.h[0] = t0.h - zoff;
  r.h[1] = t1.h - zoff;
  r.h[2] = t2.h - zoff;
  r.h[3] = t3.h - zoff;
  return r.v;
}

// 128x128 block tile, BK=32, 4 waves split 1x4 along N (each wave 128m x 32n,
// mt=8 x nt=2 MFMA 16x16x32_f16). A staged regs->LDS (fp16, Marlin k-order);
// B register-direct from packed int4 (2 dwords/wave/K-step).
template <bool PRE>
__global__ __launch_bounds__(256, 3) void gptq_gemm(
    const float* __restrict__ X32,      // f32 [M][K] (used when !PRE)
    const _Float16* __restrict__ X16,   // fp16 [M][K] pre-converted (when PRE)
    const int* __restrict__ QW,         // int32 [K/8][N]
    const int* __restrict__ QZ,         // int32 [1][N/8]
    const float* __restrict__ SC,       // f32 [1][N]
    float* __restrict__ OUT) {          // f32 [M][N]
  const int tid  = threadIdx.x;
  const int lane = tid & 63;
  const int wave = tid >> 6;          // n-split: wave covers n in [32*wave, 32*wave+32)
  const int quad = lane >> 4;
  const int l16  = lane & 15;
  const int bx = blockIdx.x;          // 86 N-tiles
  const int by = blockIdx.y;          // 32 M-tiles

  __shared__ half8 ldsA[512];         // [kb:4][m:128], 16B chunks, 8 KB

  // Staging: thread t owns chunks (kb=t>>7, m=t&127) and (kb+2, m); LDS idx = t, t+256.
  const int mrow = by * 128 + (tid & 127);
  const half8*  gx16 = PRE ? (const half8*)(X16 + (size_t)mrow * K_DIM) + (tid >> 7) : nullptr;
  const float4* gx32 = !PRE ? (const float4*)(X32 + (size_t)mrow * K_DIM) + (tid >> 7) * 2 : nullptr;

  // B: packed row 4*ks+quad, col n0 = bx*128 + wave*32 + l16 (+16 for nt=1).
  const int* qp = QW + (size_t)quad * N_DIM + bx * 128 + wave * 32 + l16;

  half2v zoff[2];
  float sc[2];
#pragma unroll
  for (int nt = 0; nt < 2; ++nt) {
    int n = bx * 128 + wave * 32 + nt * 16 + l16;
    int z = (QZ[n >> 3] >> ((n & 7) * 4)) & 15;
    union { unsigned int u; half2v h; } zc;
    unsigned int zb = 0x6400u + (unsigned int)(z + 1);   // fp16 bits of 1025+z (exact)
    zc.u = (zb << 16) | zb;
    zoff[nt] = zc.h;
    sc[nt] = SC[n];
  }

  f32x4 acc[8][2] = {};

  // Prefetch iteration 0.
  half8 va = {}, vb = {};
  float4 f0 = {}, f1 = {}, f2 = {}, f3 = {};
  if (PRE) { va = gx16[0]; vb = gx16[2]; }
  else     { f0 = gx32[0]; f1 = gx32[1]; f2 = gx32[4]; f3 = gx32[5]; }
  int q0 = qp[0], q1 = qp[16];

  for (int ks = 0; ks < 128; ++ks) {
    __syncthreads();  // previous iteration's ds_reads complete
    if (PRE) {
      ldsA[tid]       = va;
      ldsA[tid + 256] = vb;
    } else {
      ldsA[tid]       = pack8(f0, f1);
      ldsA[tid + 256] = pack8(f2, f3);
    }

    // Prefetch next iteration.
    half8 nva = va, nvb = vb;
    float4 nf0 = f0, nf1 = f1, nf2 = f2, nf3 = f3;
    int nq0 = q0, nq1 = q1;
    if (ks < 127) {
      qp += 4 * N_DIM;
      nq0 = qp[0]; nq1 = qp[16];
      if (PRE) { gx16 += 4; nva = gx16[0]; nvb = gx16[2]; }
      else     { gx32 += 8; nf0 = gx32[0]; nf1 = gx32[1]; nf2 = gx32[4]; nf3 = gx32[5]; }
    }
    __syncthreads();  // staging visible

    half8 b0 = unpack8((unsigned int)q0, zoff[0]);
    half8 b1 = unpack8((unsigned int)q1, zoff[1]);
#pragma unroll
    for (int mt = 0; mt < 8; ++mt) {
      half8 a = ldsA[quad * 128 + mt * 16 + l16];
      acc[mt][0] = __builtin_amdgcn_mfma_f32_16x16x32_f16(a, b0, acc[mt][0], 0, 0, 0);
      acc[mt][1] = __builtin_amdgcn_mfma_f32_16x16x32_f16(a, b1, acc[mt][1], 0, 0, 0);
    }

    va = nva; vb = nvb;
    f0 = nf0; f1 = nf1; f2 = nf2; f3 = nf3;
    q0 = nq0; q1 = nq1;
  }

  // Epilogue: C/D layout col=lane&15, row=quad*4+reg (dtype-independent, m89/m121).
#pragma unroll
  for (int mt = 0; mt < 8; ++mt) {
    int mbase = by * 128 + mt * 16 + quad * 4;
#pragma unroll
    for (int nt = 0; nt < 2; ++nt) {
      int n = bx * 128 + wave * 32 + nt * 16 + l16;
      float s = sc[nt];
#pragma unroll
      for (int p = 0; p < 4; ++p) {
        OUT[(size_t)(mbase + p) * N_DIM + n] = acc[mt][nt][p] * s;
      }
    }
  }
}

extern "C" void kernel_launch(void* const* d_in, const int* in_sizes, int n_in,
                              void* d_out, int out_size, void* d_ws, size_t ws_size,
                              hipStream_t stream) {
  const float* X  = (const float*)d_in[0];
  const int* QW   = (const int*)d_in[1];
  const int* QZ   = (const int*)d_in[2];
  const float* SC = (const float*)d_in[3];
  float* OUT      = (float*)d_out;

  dim3 grid(N_DIM / 128, M_DIM / 128);
  const size_t x16_bytes = (size_t)M_DIM * K_DIM * sizeof(_Float16);  // 32 MiB

  if (ws_size >= x16_bytes) {
    _Float16* X16 = (_Float16*)d_ws;
    convert_x<<<dim3((M_DIM * (size_t)K_DIM / 8) / 256), 256, 0, stream>>>(X, X16);
    gptq_gemm<true><<<grid, 256, 0, stream>>>(X, X16, QW, QZ, SC, OUT);
  } else {
    gptq_gemm<false><<<grid, 256, 0, stream>>>(X, nullptr, QW, QZ, SC, OUT);
  }
}

// Round 8
// 659.526 us; speedup vs baseline: 1.2082x; 1.2082x over previous
//
#include <hip/hip_runtime.h>
#include <stdint.h>

#define M_DIM 4096
#define K_DIM 4096
#define N_DIM 11008

typedef _Float16 half2v __attribute__((ext_vector_type(2)));
typedef _Float16 half8  __attribute__((ext_vector_type(8)));
typedef float    f32x4  __attribute__((ext_vector_type(4)));

// cvt_pkrtz returns __fp16x2; route through bits (clang _Float16/__fp16 mismatch).
__device__ __forceinline__ unsigned int pkrtz_bits(float a, float b) {
  typedef __fp16 fp16x2 __attribute__((ext_vector_type(2)));
  union { fp16x2 h; unsigned int u; } c;
  c.h = __builtin_amdgcn_cvt_pkrtz(a, b);
  return c.u;
}

// Pack 8 f32 (exactly-fp16-valued) into fp16, Marlin order {0,4,1,5,2,6,3,7}.
__device__ __forceinline__ half8 pack8(float4 lo, float4 hi) {
  union { unsigned int u[4]; half8 v; } r;
  r.u[0] = pkrtz_bits(lo.x, hi.x);
  r.u[1] = pkrtz_bits(lo.y, hi.y);
  r.u[2] = pkrtz_bits(lo.z, hi.z);
  r.u[3] = pkrtz_bits(lo.w, hi.w);
  return r.v;
}

// Pre-pass: X f32 [M][K] -> fp16 [M][K], k-permuted within each octet.
__global__ __launch_bounds__(256) void convert_x(const float* __restrict__ X,
                                                 _Float16* __restrict__ X16) {
  size_t g = (size_t)blockIdx.x * 256 + threadIdx.x;
  const float4* p = (const float4*)(X + g * 8);
  float4 lo = p[0], hi = p[1];
  *(half8*)(X16 + g * 8) = pack8(lo, hi);
}

// 8 nibbles -> 8 fp16 (q - (z+1)), Marlin order; zoff = half2(1025+z,1025+z).
__device__ __forceinline__ half8 unpack8(unsigned int q, half2v zoff) {
  union { unsigned int u; half2v h; } t0, t1, t2, t3;
  t0.u = (q & 0x000F000Fu) | 0x64006400u;
  t1.u = ((q >> 4) & 0x000F000Fu) | 0x64006400u;
  t2.u = ((q >> 8) & 0x000F000Fu) | 0x64006400u;
  t3.u = ((q >> 12) & 0x000F000Fu) | 0x64006400u;
  union { half2v h[4]; half8 v; } r;
  r.h[0] = t0.h - zoff;
  r.h[1] = t1.h - zoff;
  r.h[2] = t2.h - zoff;
  r.h[3] = t3.h - zoff;
  return r.v;
}

// Async global->LDS, 16B/lane. LDS dst = wave-uniform base + lane*16 (m97 pattern).
__device__ __forceinline__ void stage16(const void* g, void* l) {
  __builtin_amdgcn_global_load_lds((__attribute__((address_space(1))) unsigned int*)g,
                                   (__attribute__((address_space(3))) unsigned int*)l,
                                   16, 0, 0);
}

// 128x128 block, BK=64, double-buffered LDS (2x16KB), ONE barrier per stage.
// 4 waves in 2x2 grid, each 64m x 64n = 4x4 MFMA 16x16x32_f16.
// A: global_load_lds -> LDS [buf][octet:8][m:128] 16B chunks.
// B: register-direct packed int4, prefetched one stage ahead; staging + prefetch
// issue at stage TOP so the barrier's vmcnt(0) drain is hidden behind compute.
__global__ __launch_bounds__(256, 3) void gptq_gemm(
    const _Float16* __restrict__ X16,   // fp16 [M][K], Marlin octet order (d_ws)
    const int* __restrict__ QW,         // int32 [K/8][N]
    const int* __restrict__ QZ,         // int32 [1][N/8]
    const float* __restrict__ SC,       // f32 [1][N]
    float* __restrict__ OUT) {          // f32 [M][N]
  const int tid  = threadIdx.x;
  const int lane = tid & 63;
  const int wave = tid >> 6;
  const int wr   = wave >> 1;
  const int wc   = wave & 1;
  const int quad = lane >> 4;
  const int l16  = lane & 15;
  const int bx = blockIdx.x;   // 86
  const int by = blockIdx.y;   // 32

  __shared__ __align__(16) _Float16 ldsA[2 * 1024 * 8];  // 32 KB

  // Staging: thread t stages chunks c_i = i*256+t (i=0..3); octet=c>>7, m=c&127.
  const _Float16* gA = X16 + (size_t)(by * 128 + (tid & 127)) * K_DIM + (tid >> 7) * 8;
  _Float16* lA = ldsA + (size_t)tid * 8;

  // B: frag row (stage ks, step s) = ks*8 + s*4 + quad; col = bx*128+wc*64+nt*16+l16.
  const int* qp = QW + (size_t)quad * N_DIM + bx * 128 + wc * 64 + l16;

  half2v zoff[4];
  float sc[4];
#pragma unroll
  for (int nt = 0; nt < 4; ++nt) {
    int n = bx * 128 + wc * 64 + nt * 16 + l16;
    int z = (QZ[n >> 3] >> ((n & 7) * 4)) & 15;
    union { unsigned int u; half2v h; } zc;
    unsigned int zb = 0x6400u + (unsigned int)(z + 1);   // fp16 bits of 1025+z
    zc.u = (zb << 16) | zb;
    zoff[nt] = zc.h;
    sc[nt] = SC[n];
  }

  f32x4 acc[4][4] = {};

  // Prologue: stage 0 -> buf 0; prefetch B stage 0.
#pragma unroll
  for (int i = 0; i < 4; ++i)
    stage16(gA + i * 16, lA + i * 2048);
  int q[2][4];
#pragma unroll
  for (int s = 0; s < 2; ++s)
#pragma unroll
    for (int nt = 0; nt < 4; ++nt)
      q[s][nt] = qp[(s * 4) * N_DIM + nt * 16];
  __syncthreads();   // drains staging: buf 0 ready

  int p = 0;
  for (int ks = 0; ks < 64; ++ks) {
    // Issue next stage's A-staging (into other buffer) + B prefetch FIRST.
    int nq[2][4];
    if (ks < 63) {
      gA += 64;
      qp += 8 * N_DIM;
      _Float16* lb = ldsA + (p ^ 1) * 8192 + (size_t)tid * 8;
#pragma unroll
      for (int i = 0; i < 4; ++i)
        stage16(gA + i * 16, lb + i * 2048);
#pragma unroll
      for (int s = 0; s < 2; ++s)
#pragma unroll
        for (int nt = 0; nt < 4; ++nt)
          nq[s][nt] = qp[(s * 4) * N_DIM + nt * 16];
    }

    // Compute current stage from buf p (2 K=32 steps).
    const _Float16* base = ldsA + p * 8192;
#pragma unroll
    for (int s = 0; s < 2; ++s) {
      half8 a[4];
#pragma unroll
      for (int mt = 0; mt < 4; ++mt)
        a[mt] = *(const half8*)(base + ((s * 4 + quad) * 128 + wr * 64 + mt * 16 + l16) * 8);
      half8 b[4];
#pragma unroll
      for (int nt = 0; nt < 4; ++nt)
        b[nt] = unpack8((unsigned int)q[s][nt], zoff[nt]);
#pragma unroll
      for (int mt = 0; mt < 4; ++mt)
#pragma unroll
        for (int nt = 0; nt < 4; ++nt)
          acc[mt][nt] = __builtin_amdgcn_mfma_f32_16x16x32_f16(a[mt], b[nt], acc[mt][nt], 0, 0, 0);
    }
    __syncthreads();   // single barrier: next buf staged + this buf's reads done
    if (ks < 63) {
#pragma unroll
      for (int s = 0; s < 2; ++s)
#pragma unroll
        for (int nt = 0; nt < 4; ++nt)
          q[s][nt] = nq[s][nt];
    }
    p ^= 1;
  }

  // Epilogue: C/D layout col=lane&15, row=quad*4+reg (m89-verified).
#pragma unroll
  for (int mt = 0; mt < 4; ++mt) {
    int mbase = by * 128 + wr * 64 + mt * 16 + quad * 4;
#pragma unroll
    for (int nt = 0; nt < 4; ++nt) {
      int n = bx * 128 + wc * 64 + nt * 16 + l16;
      float s = sc[nt];
#pragma unroll
      for (int pp = 0; pp < 4; ++pp)
        OUT[(size_t)(mbase + pp) * N_DIM + n] = acc[mt][nt][pp] * s;
    }
  }
}

extern "C" void kernel_launch(void* const* d_in, const int* in_sizes, int n_in,
                              void* d_out, int out_size, void* d_ws, size_t ws_size,
                              hipStream_t stream) {
  const float* X  = (const float*)d_in[0];
  const int* QW   = (const int*)d_in[1];
  const int* QZ   = (const int*)d_in[2];
  const float* SC = (const float*)d_in[3];
  float* OUT      = (float*)d_out;
  _Float16* X16   = (_Float16*)d_ws;   // 32 MiB; PRE path verified on HW in round 7

  convert_x<<<dim3((M_DIM * (size_t)K_DIM / 8) / 256), 256, 0, stream>>>(X, X16);
  dim3 grid(N_DIM / 128, M_DIM / 128);
  gptq_gemm<<<grid, 256, 0, stream>>>(X16, QW, QZ, SC, OUT);
}